// Round 16
// baseline (115.143 us; speedup 1.0000x reference)
//
#include <hip/hip_runtime.h>
#include <hip/hip_bf16.h>

#define BATCH 262144
#define NSITES 64
#define NJ 2                    // j-tiles per wave (32 batch elems/wave)
#define BLOCK_BATCH 128         // batch elems per 256-thread block

typedef __attribute__((ext_vector_type(8))) short short8;
typedef __attribute__((ext_vector_type(4))) float f32x4;

// slot k = [k4 k3 | k2 k1 k0] -> logical chi = 16*k2 + 4*(k4k3) + (k1k0)
__device__ __forceinline__ int qmap(int k) {
  return (((k >> 2) & 1) << 4) | (((k >> 3) & 3) << 2) | (k & 3);
}

// pack: element idx = ((p*4 + f)*64 + l)*8 + t   (chunk = 16B = 8 bf16)
// f = m*2 + h ; l = g*16 + col ; value = bf16(cores[p][qmap(8g+t)][m][h*16+col] - delta)
// step s (1..63) reads panel p = s-1 at byte offset p*4096 + f*1024 + l*16.
__global__ void pack_E(const float* __restrict__ cores, unsigned short* __restrict__ Ep) {
  int idx = blockIdx.x * 256 + threadIdx.x;
  if (idx >= (NSITES - 1) * 2048) return;
  int t = idx & 7;
  int l = (idx >> 3) & 63;
  int f = (idx >> 9) & 3;
  int p = idx >> 11;
  int g = l >> 4, col = l & 15;
  int m = f >> 1, h = f & 1;
  int k = 8 * g + t, c = h * 16 + col;
  int b = qmap(k);
  float val = cores[((p * 32 + b) * 2 + m) * 32 + c] - ((b == c) ? 1.0f : 0.0f);
  __hip_bfloat16 hv = __float2bfloat16(val);
  Ep[idx] = *(unsigned short*)&hv;
}

#define BODYJ(jj, xx0, xx1)                                                     \
  {                                                                             \
    union { short8 s8; __hip_bfloat162 h2[4]; } vb;                             \
    vb.h2[0] = __float22bfloat162_rn(make_float2(v[jj][0], v[jj][1]));          \
    vb.h2[1] = __float22bfloat162_rn(make_float2(v[jj][2], v[jj][3]));          \
    vb.h2[2] = __float22bfloat162_rn(make_float2(v[jj][4], v[jj][5]));          \
    vb.h2[3] = __float22bfloat162_rn(make_float2(v[jj][6], v[jj][7]));          \
    const f32x4 z = {0.f, 0.f, 0.f, 0.f};                                       \
    __builtin_amdgcn_s_setprio(1);                                              \
    f32x4 r0lo = __builtin_amdgcn_mfma_f32_16x16x32_bf16(A0, vb.s8, z, 0, 0, 0); \
    f32x4 r0hi = __builtin_amdgcn_mfma_f32_16x16x32_bf16(A1, vb.s8, z, 0, 0, 0); \
    f32x4 r1lo = __builtin_amdgcn_mfma_f32_16x16x32_bf16(A2, vb.s8, z, 0, 0, 0); \
    f32x4 r1hi = __builtin_amdgcn_mfma_f32_16x16x32_bf16(A3, vb.s8, z, 0, 0, 0); \
    __builtin_amdgcn_s_setprio(0);                                              \
    const float ss = (xx0) + (xx1);                                             \
    _Pragma("unroll") for (int t = 0; t < 4; ++t) {                             \
      v[jj][t] = ss * v[jj][t] + (xx0)*r0lo[t] + (xx1)*r1lo[t];                 \
      v[jj][4 + t] = ss * v[jj][4 + t] + (xx0)*r0hi[t] + (xx1)*r1hi[t];         \
    }                                                                           \
  }

__global__ __launch_bounds__(256, 8) void mps_chain_kernel(
    const float* __restrict__ X, const float* __restrict__ core0,
    const float* __restrict__ coreN, const unsigned short* __restrict__ Ep,
    float* __restrict__ out) {
  const int tid = threadIdx.x;
  const int lane = tid & 63;
  const int wave = tid >> 6;
  const int col = lane & 15;  // batch column within 16-wide tile
  const int g = lane >> 4;    // k-group (slots 8g..8g+7)
  const int abase = blockIdx.x * BLOCK_BATCH + wave * (16 * NJ);

  // ---- phase stagger: de-align co-resident waves' stall windows ----
  switch (wave) {
    case 1: __builtin_amdgcn_s_sleep(5);  break;   // ~320 cyc
    case 2: __builtin_amdgcn_s_sleep(10); break;   // ~640 cyc
    case 3: __builtin_amdgcn_s_sleep(15); break;   // ~960 cyc
    default: break;
  }

  // ---- v0 = X[0] @ core0 ----
  float c0[2][8];
#pragma unroll
  for (int m = 0; m < 2; ++m)
#pragma unroll
    for (int t = 0; t < 8; ++t) c0[m][t] = core0[m * 32 + qmap(8 * g + t)];

  float v[NJ][8];
#pragma unroll
  for (int jj = 0; jj < NJ; ++jj) {
    const float2 xj = *(const float2*)(X + 2 * (size_t)(abase + jj * 16 + col));
#pragma unroll
    for (int t = 0; t < 8; ++t) v[jj][t] = xj.x * c0[0][t] + xj.y * c0[1][t];
  }

  // ---- main chain: NO barriers, NO LDS, all loads at-use; free-running waves ----
  const char* ep_base = (const char*)Ep + (size_t)lane * 16;
  const float* xs = X + 2 * ((size_t)BATCH + abase + col);

#pragma unroll 1
  for (int s = 1; s < NSITES; ++s) {
    const short8* ep = (const short8*)ep_base;
    const short8 A0 = ep[0], A1 = ep[64], A2 = ep[128], A3 = ep[192];

    float2 xj[NJ];
#pragma unroll
    for (int jj = 0; jj < NJ; ++jj)
      xj[jj] = *(const float2*)(xs + 2 * (jj * 16));

    BODYJ(0, xj[0].x, xj[0].y);
    BODYJ(1, xj[1].x, xj[1].y);

    ep_base += 4096;
    xs += 2 * (size_t)BATCH;
  }

  // ---- epilogue: out = |v @ coreN| ----
  float cN[8][2];
#pragma unroll
  for (int t = 0; t < 8; ++t) {
    cN[t][0] = coreN[qmap(8 * g + t) * 2 + 0];
    cN[t][1] = coreN[qmap(8 * g + t) * 2 + 1];
  }
#pragma unroll
  for (int jj = 0; jj < NJ; ++jj) {
    float p0 = 0.f, p1 = 0.f;
#pragma unroll
    for (int t = 0; t < 8; ++t) {
      p0 += v[jj][t] * cN[t][0];
      p1 += v[jj][t] * cN[t][1];
    }
    p0 += __shfl_xor(p0, 16);
    p0 += __shfl_xor(p0, 32);
    p1 += __shfl_xor(p1, 16);
    p1 += __shfl_xor(p1, 32);
    if (g == 0) {
      const int a = abase + jj * 16 + col;
      out[2 * a] = fabsf(p0);
      out[2 * a + 1] = fabsf(p1);
    }
  }
}

extern "C" void kernel_launch(void* const* d_in, const int* in_sizes, int n_in,
                              void* d_out, int out_size, void* d_ws, size_t ws_size,
                              hipStream_t stream) {
  const float* X = (const float*)d_in[0];
  const float* core0 = (const float*)d_in[1];
  const float* cores = (const float*)d_in[2];
  const float* coreN = (const float*)d_in[3];
  float* out = (float*)d_out;
  unsigned short* Ep = (unsigned short*)d_ws;  // 258048 bytes

  hipLaunchKernelGGL(pack_E, dim3(((NSITES - 1) * 2048 + 255) / 256), dim3(256), 0, stream,
                     cores, Ep);
  hipLaunchKernelGGL(mps_chain_kernel, dim3(BATCH / BLOCK_BATCH), dim3(256), 0, stream, X,
                     core0, coreN, Ep, out);
}

// Round 17
// 101.857 us; speedup vs baseline: 1.1304x; 1.1304x over previous
//
#include <hip/hip_runtime.h>
#include <hip/hip_bf16.h>

#define BATCH 262144
#define NSITES 64
#define NJ 4                    // j-tiles per wave (64 batch elems/wave)
#define BLOCK_BATCH 256         // batch elems per 256-thread block

typedef __attribute__((ext_vector_type(8))) short short8;
typedef __attribute__((ext_vector_type(4))) float f32x4;
typedef __attribute__((ext_vector_type(2))) float f32x2;

#define LOH2(r) (__builtin_shufflevector((r), (r), 0, 1))
#define HIH2(r) (__builtin_shufflevector((r), (r), 2, 3))

// slot k = [k4 k3 | k2 k1 k0] -> logical chi = 16*k2 + 4*(k4k3) + (k1k0)
__device__ __forceinline__ int qmap(int k) {
  return (((k >> 2) & 1) << 4) | (((k >> 3) & 3) << 2) | (k & 3);
}

// pack: element idx = ((p*4 + f)*64 + l)*8 + t   (chunk = 16B = 8 bf16)
// f = m*2 + h ; l = g*16 + col ; value = bf16(cores[p][qmap(8g+t)][m][h*16+col] - delta)
// step s (1..63) reads panel p = s-1 at byte offset p*4096 + f*1024 + l*16.
__global__ void pack_E(const float* __restrict__ cores, unsigned short* __restrict__ Ep) {
  int idx = blockIdx.x * 256 + threadIdx.x;
  if (idx >= (NSITES - 1) * 2048) return;
  int t = idx & 7;
  int l = (idx >> 3) & 63;
  int f = (idx >> 9) & 3;
  int p = idx >> 11;
  int g = l >> 4, col = l & 15;
  int m = f >> 1, h = f & 1;
  int k = 8 * g + t, c = h * 16 + col;
  int b = qmap(k);
  float val = cores[((p * 32 + b) * 2 + m) * 32 + c] - ((b == c) ? 1.0f : 0.0f);
  __hip_bfloat16 hv = __float2bfloat16(val);
  Ep[idx] = *(unsigned short*)&hv;
}

// packed-f32 state: w[jj][q] = v elements {2q, 2q+1}
#define BODYJ(jj, xx0, xx1)                                                     \
  {                                                                             \
    union { short8 s8; __hip_bfloat162 h2[4]; } vb;                             \
    vb.h2[0] = __float22bfloat162_rn(make_float2(w[jj][0][0], w[jj][0][1]));    \
    vb.h2[1] = __float22bfloat162_rn(make_float2(w[jj][1][0], w[jj][1][1]));    \
    vb.h2[2] = __float22bfloat162_rn(make_float2(w[jj][2][0], w[jj][2][1]));    \
    vb.h2[3] = __float22bfloat162_rn(make_float2(w[jj][3][0], w[jj][3][1]));    \
    const f32x4 z = {0.f, 0.f, 0.f, 0.f};                                       \
    __builtin_amdgcn_s_setprio(1);                                              \
    f32x4 r0lo = __builtin_amdgcn_mfma_f32_16x16x32_bf16(A0, vb.s8, z, 0, 0, 0); \
    f32x4 r0hi = __builtin_amdgcn_mfma_f32_16x16x32_bf16(A1, vb.s8, z, 0, 0, 0); \
    f32x4 r1lo = __builtin_amdgcn_mfma_f32_16x16x32_bf16(A2, vb.s8, z, 0, 0, 0); \
    f32x4 r1hi = __builtin_amdgcn_mfma_f32_16x16x32_bf16(A3, vb.s8, z, 0, 0, 0); \
    __builtin_amdgcn_s_setprio(0);                                              \
    const float ss = (xx0) + (xx1);                                             \
    const f32x2 sv = {ss, ss}, x0v = {(xx0), (xx0)}, x1v = {(xx1), (xx1)};      \
    w[jj][0] = sv * w[jj][0] + x0v * LOH2(r0lo) + x1v * LOH2(r1lo);             \
    w[jj][1] = sv * w[jj][1] + x0v * HIH2(r0lo) + x1v * HIH2(r1lo);             \
    w[jj][2] = sv * w[jj][2] + x0v * LOH2(r0hi) + x1v * LOH2(r1hi);             \
    w[jj][3] = sv * w[jj][3] + x0v * HIH2(r0hi) + x1v * HIH2(r1hi);             \
  }

__global__ __launch_bounds__(256, 4) void mps_chain_kernel(
    const float* __restrict__ X, const float* __restrict__ core0,
    const float* __restrict__ coreN, const unsigned short* __restrict__ Ep,
    float* __restrict__ out) {
  const int tid = threadIdx.x;
  const int lane = tid & 63;
  const int wave = tid >> 6;
  const int col = lane & 15;  // batch column within 16-wide tile
  const int g = lane >> 4;    // k-group (slots 8g..8g+7)
  const int abase = blockIdx.x * BLOCK_BATCH + wave * (16 * NJ);

  // ---- v0 = X[0] @ core0 ----
  float c0[2][8];
#pragma unroll
  for (int m = 0; m < 2; ++m)
#pragma unroll
    for (int t = 0; t < 8; ++t) c0[m][t] = core0[m * 32 + qmap(8 * g + t)];

  f32x2 w[NJ][4];
#pragma unroll
  for (int jj = 0; jj < NJ; ++jj) {
    const float2 xj = *(const float2*)(X + 2 * (size_t)(abase + jj * 16 + col));
#pragma unroll
    for (int q = 0; q < 4; ++q) {
      w[jj][q][0] = xj.x * c0[0][2 * q] + xj.y * c0[1][2 * q];
      w[jj][q][1] = xj.x * c0[0][2 * q + 1] + xj.y * c0[1][2 * q + 1];
    }
  }

  // ---- X register prefetch, distance 1 ----
  const float* xs = X + 2 * (size_t)(abase + col);
  float xl[NJ], xh[NJ];
#pragma unroll
  for (int jj = 0; jj < NJ; ++jj) {
    const float2 t_ = *(const float2*)(xs + 2 * ((size_t)BATCH + jj * 16));
    xl[jj] = t_.x;
    xh[jj] = t_.y;
  }

  // ---- main chain: no barriers, no LDS; E at-use from L1, X one step ahead ----
  const char* ep_base = (const char*)Ep + (size_t)lane * 16;

#pragma unroll 1
  for (int s = 1; s < NSITES; ++s) {
    // prefetch X(s+1) into registers (consumed next iteration)
    const size_t sx = (s + 1 < NSITES) ? (size_t)(s + 1) : (size_t)(NSITES - 1);
    float2 xn[NJ];
#pragma unroll
    for (int jj = 0; jj < NJ; ++jj)
      xn[jj] = *(const float2*)(xs + 2 * (sx * BATCH + jj * 16));

    // E fragments for this step (L1-hot: same 4KB panel for all waves on the CU)
    const short8* ep = (const short8*)ep_base;
    const short8 A0 = ep[0], A1 = ep[64], A2 = ep[128], A3 = ep[192];

    BODYJ(0, xl[0], xh[0]);
    BODYJ(1, xl[1], xh[1]);
    BODYJ(2, xl[2], xh[2]);
    BODYJ(3, xl[3], xh[3]);

#pragma unroll
    for (int jj = 0; jj < NJ; ++jj) {
      xl[jj] = xn[jj].x;
      xh[jj] = xn[jj].y;
    }
    ep_base += 4096;
  }

  // ---- epilogue: out = |v @ coreN| ----
  float cN[8][2];
#pragma unroll
  for (int t = 0; t < 8; ++t) {
    cN[t][0] = coreN[qmap(8 * g + t) * 2 + 0];
    cN[t][1] = coreN[qmap(8 * g + t) * 2 + 1];
  }
#pragma unroll
  for (int jj = 0; jj < NJ; ++jj) {
    float p0 = 0.f, p1 = 0.f;
#pragma unroll
    for (int t = 0; t < 8; ++t) {
      p0 += w[jj][t >> 1][t & 1] * cN[t][0];
      p1 += w[jj][t >> 1][t & 1] * cN[t][1];
    }
    p0 += __shfl_xor(p0, 16);
    p0 += __shfl_xor(p0, 32);
    p1 += __shfl_xor(p1, 16);
    p1 += __shfl_xor(p1, 32);
    if (g == 0) {
      const int a = abase + jj * 16 + col;
      out[2 * a] = fabsf(p0);
      out[2 * a + 1] = fabsf(p1);
    }
  }
}

extern "C" void kernel_launch(void* const* d_in, const int* in_sizes, int n_in,
                              void* d_out, int out_size, void* d_ws, size_t ws_size,
                              hipStream_t stream) {
  const float* X = (const float*)d_in[0];
  const float* core0 = (const float*)d_in[1];
  const float* cores = (const float*)d_in[2];
  const float* coreN = (const float*)d_in[3];
  float* out = (float*)d_out;
  unsigned short* Ep = (unsigned short*)d_ws;  // 258048 bytes

  hipLaunchKernelGGL(pack_E, dim3(((NSITES - 1) * 2048 + 255) / 256), dim3(256), 0, stream,
                     cores, Ep);
  hipLaunchKernelGGL(mps_chain_kernel, dim3(BATCH / BLOCK_BATCH), dim3(256), 0, stream, X,
                     core0, coreN, Ep, out);
}